// Round 2
// baseline (1863.331 us; speedup 1.0000x reference)
//
#include <hip/hip_runtime.h>

// Problem constants (B=64, S=512, D=512, K=4096)
#define N_ROWS 32768          // B*S
#define DIM    512
#define KCODES 4096
#define Q_ELEMS (N_ROWS * DIM)      // 16777216
#define LOSS_OFF Q_ELEMS            // 1 float
#define IDX_OFF (Q_ELEMS + 1)       // 32768 floats

// ---------------- Kernel 1a: codebook norms ||c_k||^2 (fp32) ----------------
__global__ void k_cnorm(const float* __restrict__ cb, float* __restrict__ cnorm) {
    int wave = (blockIdx.x * blockDim.x + threadIdx.x) >> 6;
    int lane = threadIdx.x & 63;
    if (wave >= KCODES) return;
    const float4* row = (const float4*)(cb + (size_t)wave * DIM);
    float4 v1 = row[lane];
    float4 v2 = row[lane + 64];
    float s = v1.x*v1.x + v1.y*v1.y + v1.z*v1.z + v1.w*v1.w
            + v2.x*v2.x + v2.y*v2.y + v2.z*v2.z + v2.w*v2.w;
    #pragma unroll
    for (int m = 32; m >= 1; m >>= 1) s += __shfl_xor(s, m);
    if (lane == 0) cnorm[wave] = s;
}

// ---------------- Kernel 1b: input row norms ||x_n||^2 (fp32) ----------------
// Any fp32 summation order works: the reference's dist rounding is
// translation-invariant to grid-multiple differences in xnorm.
__global__ void k_xnorm(const float* __restrict__ x, float* __restrict__ xnorm) {
    int wave = (blockIdx.x * blockDim.x + threadIdx.x) >> 6;
    int lane = threadIdx.x & 63;
    if (wave >= N_ROWS) return;
    const float4* row = (const float4*)(x + (size_t)wave * DIM);
    float4 v1 = row[lane];
    float4 v2 = row[lane + 64];
    float s = v1.x*v1.x + v1.y*v1.y + v1.z*v1.z + v1.w*v1.w
            + v2.x*v2.x + v2.y*v2.y + v2.z*v2.z + v2.w*v2.w;
    #pragma unroll
    for (int m = 32; m >= 1; m >>= 1) s += __shfl_xor(s, m);
    if (lane == 0) xnorm[wave] = s;
}

// ---------------- Kernel 2: fp32-formula distance + argmin ----------------
// Replicates the reference's fp32 arithmetic:
//   dist32(n,k) = fl32( fl32(xnorm32[n] + cnorm32[k]) - fl32(2 * dot(n,k)) )
// argmin over k with FIRST-index tie-break (ties are common: dist is on the
// ulp(512)=6.1e-5 grid while score spread is only ~6e-3).
// dot accumulated as a sequential-d fp32 fma chain (matches sgemm's chain).
#define BM 64
#define BN 128
#define BD 32

__global__ __launch_bounds__(256)
void k_argmin(const float* __restrict__ x, const float* __restrict__ cb,
              const float* __restrict__ cnorm, const float* __restrict__ xnorm,
              int* __restrict__ idx_ws, float* __restrict__ idx_out) {
    __shared__ float xs[BM][BD + 4];   // row stride 36: 2-way banks on read, fine
    __shared__ float cs[BD][BN];       // transposed: cs[d][k]

    const int tid = threadIdx.x;
    const int ty = tid >> 4;           // 0..15
    const int tx = tid & 15;           // 0..15
    const int r0 = blockIdx.x * BM;

    float xn[4];
    #pragma unroll
    for (int i = 0; i < 4; ++i) xn[i] = xnorm[r0 + ty * 4 + i];

    float best[4];
    int   bidx[4];
    #pragma unroll
    for (int i = 0; i < 4; ++i) { best[i] = 3.4e38f; bidx[i] = 0; }

    for (int kc = 0; kc < KCODES; kc += BN) {
        float acc[4][8];
        #pragma unroll
        for (int i = 0; i < 4; ++i)
            #pragma unroll
            for (int j = 0; j < 8; ++j) acc[i][j] = 0.f;

        for (int dc = 0; dc < DIM; dc += BD) {
            // stage x tile: 64 rows x 32 d
            #pragma unroll
            for (int it = 0; it < 2; ++it) {
                int f = tid + it * 256;
                int row = f >> 3;
                int dq  = f & 7;
                float4 v = *(const float4*)(x + (size_t)(r0 + row) * DIM + dc + dq * 4);
                *(float4*)&xs[row][dq * 4] = v;
            }
            // stage code tile transposed: 128 codes x 32 d
            #pragma unroll
            for (int it = 0; it < 4; ++it) {
                int k  = tid & 127;
                int dq = (tid >> 7) + it * 2;
                float4 v = *(const float4*)(cb + (size_t)(kc + k) * DIM + dc + dq * 4);
                cs[dq * 4 + 0][k] = v.x;
                cs[dq * 4 + 1][k] = v.y;
                cs[dq * 4 + 2][k] = v.z;
                cs[dq * 4 + 3][k] = v.w;
            }
            __syncthreads();

            // thread's codes within tile: {tx*4 .. tx*4+3} and {64+tx*4 .. +3}
            // (two 16B reads at stride 16B*tx -> 2-way bank groups, ~free)
            #pragma unroll 8
            for (int d = 0; d < BD; ++d) {
                float a[4];
                #pragma unroll
                for (int i = 0; i < 4; ++i) a[i] = xs[ty * 4 + i][d];
                float4 b0 = *(const float4*)&cs[d][tx * 4];
                float4 b1 = *(const float4*)&cs[d][64 + tx * 4];
                #pragma unroll
                for (int i = 0; i < 4; ++i) {
                    acc[i][0] = fmaf(a[i], b0.x, acc[i][0]);
                    acc[i][1] = fmaf(a[i], b0.y, acc[i][1]);
                    acc[i][2] = fmaf(a[i], b0.z, acc[i][2]);
                    acc[i][3] = fmaf(a[i], b0.w, acc[i][3]);
                    acc[i][4] = fmaf(a[i], b1.x, acc[i][4]);
                    acc[i][5] = fmaf(a[i], b1.y, acc[i][5]);
                    acc[i][6] = fmaf(a[i], b1.z, acc[i][6]);
                    acc[i][7] = fmaf(a[i], b1.w, acc[i][7]);
                }
            }
            __syncthreads();
        }

        // scores in reference fp32 order; k ascending (half-major) per thread
        #pragma unroll
        for (int half = 0; half < 2; ++half) {
            #pragma unroll
            for (int j = 0; j < 4; ++j) {
                int k = kc + half * 64 + tx * 4 + j;
                float cn = cnorm[k];
                #pragma unroll
                for (int i = 0; i < 4; ++i) {
                    float t1 = xn[i] + cn;                       // fl32(xn + cn)
                    float tw = 2.0f * acc[i][half * 4 + j];      // exact x2
                    float s  = t1 - tw;                          // fl32(t1 - tw)
                    if (s < best[i]) { best[i] = s; bidx[i] = k; }
                }
            }
        }
    }

    // cross-tx reduce: strictly-smaller wins; tie -> lower index (first occurrence)
    #pragma unroll
    for (int i = 0; i < 4; ++i) {
        float b = best[i];
        int   ix = bidx[i];
        #pragma unroll
        for (int m = 1; m <= 8; m <<= 1) {
            float ob = __shfl_xor(b, m);
            int   oi = __shfl_xor(ix, m);
            if (ob < b || (ob == b && oi < ix)) { b = ob; ix = oi; }
        }
        if (tx == 0) {
            int row = r0 + ty * 4 + i;
            idx_ws[row] = ix;
            idx_out[row] = (float)ix;
        }
    }
}

// ---------------- Kernel 3: gather quantized rows + loss partials ----------------
__global__ void k_gather(const float* __restrict__ x, const float* __restrict__ cb,
                         const int* __restrict__ idx, float* __restrict__ qout,
                         float* __restrict__ partial) {
    int row  = blockIdx.x * 4 + (threadIdx.x >> 6);
    int lane = threadIdx.x & 63;
    int k = idx[row];
    const float4* crow = (const float4*)(cb + (size_t)k * DIM);
    const float4* xrow = (const float4*)(x + (size_t)row * DIM);
    float4* qrow = (float4*)(qout + (size_t)row * DIM);
    float s = 0.f;
    #pragma unroll
    for (int it = 0; it < 2; ++it) {
        int d4 = lane + it * 64;
        float4 q = crow[d4];
        float4 xi = xrow[d4];
        qrow[d4] = q;
        float dx = q.x - xi.x; s += dx * dx;
        dx = q.y - xi.y; s += dx * dx;
        dx = q.z - xi.z; s += dx * dx;
        dx = q.w - xi.w; s += dx * dx;
    }
    #pragma unroll
    for (int m = 32; m >= 1; m >>= 1) s += __shfl_xor(s, m);
    __shared__ float ws4[4];
    if (lane == 0) ws4[threadIdx.x >> 6] = s;
    __syncthreads();
    if (threadIdx.x == 0)
        partial[blockIdx.x] = (ws4[0] + ws4[1]) + (ws4[2] + ws4[3]);
}

// ---------------- Kernel 4: deterministic final loss reduce ----------------
__global__ void k_loss(const float* __restrict__ partial, float* __restrict__ out_loss) {
    int t = threadIdx.x;   // 256 threads, 8192 partials
    double s = 0.0;
    #pragma unroll 4
    for (int i = 0; i < 32; ++i) s += (double)partial[t * 32 + i];
    #pragma unroll
    for (int m = 32; m >= 1; m >>= 1) s += __shfl_xor(s, m);
    __shared__ double sd[4];
    if ((t & 63) == 0) sd[t >> 6] = s;
    __syncthreads();
    if (t == 0) {
        double tot = (sd[0] + sd[1]) + (sd[2] + sd[3]);
        out_loss[0] = (float)(1.25 * tot / (double)Q_ELEMS);
    }
}

extern "C" void kernel_launch(void* const* d_in, const int* in_sizes, int n_in,
                              void* d_out, int out_size, void* d_ws, size_t ws_size,
                              hipStream_t stream) {
    const float* x  = (const float*)d_in[0];   // [32768, 512]
    const float* cb = (const float*)d_in[1];   // [4096, 512]
    float* out = (float*)d_out;

    float* cnorm = (float*)d_ws;                                        // 4096 f
    float* xnorm = (float*)((char*)d_ws + (size_t)KCODES * 4);          // 32768 f
    int*   idxw  = (int*)((char*)d_ws + (size_t)(KCODES + N_ROWS) * 4); // 32768 i32
    float* part  = (float*)((char*)d_ws + (size_t)(KCODES + 2 * N_ROWS) * 4); // 8192 f

    k_cnorm<<<KCODES / 4, 256, 0, stream>>>(cb, cnorm);
    k_xnorm<<<N_ROWS / 4, 256, 0, stream>>>(x, xnorm);
    k_argmin<<<N_ROWS / BM, 256, 0, stream>>>(x, cb, cnorm, xnorm, idxw, out + IDX_OFF);
    k_gather<<<N_ROWS / 4, 256, 0, stream>>>(x, cb, idxw, out, part);
    k_loss<<<1, 256, 0, stream>>>(part, out + LOSS_OFF);
}